// Round 17
// baseline (137.899 us; speedup 1.0000x reference)
//
#include <hip/hip_runtime.h>

#define NB 128
#define NS 256
#define ND 256
#define NH 8
#define NHD 2048
static constexpr float EPS = 1e-5f;

typedef __attribute__((ext_vector_type(8))) short bf8v;
typedef __attribute__((ext_vector_type(4))) float f32x4;

__device__ __forceinline__ short f2bf(float f) {
  unsigned u = __float_as_uint(f);
  unsigned r = (u + 0x7fffu + ((u >> 16) & 1u)) >> 16;
  return (short)r;
}

__device__ __forceinline__ void split8(float4 a, float4 b, bf8v& hi, bf8v& lo) {
  float x[8] = {a.x, a.y, a.z, a.w, b.x, b.y, b.z, b.w};
  bf8v h, l;
#pragma unroll
  for (int i = 0; i < 8; ++i) {
    unsigned u = __float_as_uint(x[i]);
    unsigned hb = (u + 0x7fffu + ((u >> 16) & 1u)) >> 16;
    h[i] = (short)hb;
    float hf = __uint_as_float(hb << 16);
    l[i] = f2bf(x[i] - hf);
  }
  hi = h;
  lo = l;
}

__device__ __forceinline__ float block_reduce_sum(float v, float* red, int t) {
  __syncthreads();
  red[t] = v;
  __syncthreads();
  for (int off = 128; off > 0; off >>= 1) {
    if (t < off) red[t] += red[t + off];
    __syncthreads();
  }
  return red[0];
}

// ================= device bodies =================

__device__ void meta_body(int c, int sel, int t,
                          const float* __restrict__ Wk, const float* __restrict__ bk,
                          const float* __restrict__ Wv, const float* __restrict__ bv,
                          const int* __restrict__ mask_i,
                          float* __restrict__ kmeta, float* __restrict__ vmeta,
                          int* __restrict__ flag) {
  const float* W = sel ? Wv : Wk;
  const float* bvec = sel ? bv : bk;
  float* meta = sel ? vmeta : kmeta;
  __shared__ float red_m[256];
  __shared__ int sflag;
  float s_w = 0.f, s_l = 0.f;
  const float* row = W + (size_t)c * NHD;
  for (int j = t; j < NHD; j += 256) { float w = row[j]; s_w += w; s_l += w * bvec[j]; }
  s_w = block_reduce_sum(s_w, red_m, t);
  s_l = block_reduce_sum(s_l, red_m, t);
  if (t == 0) { meta[c] = s_w * (1.0f / NHD); meta[256 + c] = s_l * (2.0f / NHD); }
  if (c == 0) {
    float s_b = 0.f, s_b2 = 0.f;
    for (int j = t; j < NHD; j += 256) { float bb = bvec[j]; s_b += bb; s_b2 += bb * bb; }
    s_b = block_reduce_sum(s_b, red_m, t);
    s_b2 = block_reduce_sum(s_b2, red_m, t);
    if (t == 0) { meta[512] = s_b * (1.0f / NHD); meta[513] = s_b2 * (1.0f / NHD); }
  }
  if (c == 1 && sel == 0) {
    if (t == 0) sflag = 0;
    __syncthreads();
    int any = 0;
    for (int i = t; i < 8192; i += 256) {
      unsigned v = (unsigned)mask_i[i];
      if (v > 1u) any = 1;
    }
    if (any) atomicOr(&sflag, 1);
    __syncthreads();
    if (t == 0) flag[0] = sflag;
  }
}

// q1: 4 batches per block; each Wq element feeds 4 FMAs (weight traffic /4)
__device__ void q1_body(int h, int bg, int t,
                        const float* __restrict__ local, const float* __restrict__ Wq,
                        const float* __restrict__ bq,
                        float* __restrict__ qraw, float* __restrict__ qpart) {
  __shared__ float ls[4][256];
  __shared__ float red_q[256];
  int b0 = bg * 4;
#pragma unroll
  for (int bi = 0; bi < 4; ++bi) ls[bi][t] = local[(b0 + bi) * ND + t];
  __syncthreads();
  int j = h * 256 + t;
  float acc[4] = {0.f, 0.f, 0.f, 0.f};
  const float* W = Wq + j;
  for (int c = 0; c < 256; ++c) {
    float wv = W[(size_t)c * NHD];
#pragma unroll
    for (int bi = 0; bi < 4; ++bi) acc[bi] = fmaf(ls[bi][c], wv, acc[bi]);
  }
#pragma unroll
  for (int bi = 0; bi < 4; ++bi) {
    int b = b0 + bi;
    float a = acc[bi] + bq[j];
    qraw[(size_t)b * NHD + j] = a;
    float s1 = block_reduce_sum(a, red_q, t);
    float s2 = block_reduce_sum(a * a, red_q, t);
    if (t == 0) { qpart[(b * 8 + h) * 2] = s1; qpart[(b * 8 + h) * 2 + 1] = s2; }
  }
}

__device__ void aat2_body(int pidx, int zy, int t,
                          const float* __restrict__ Wk, const float* __restrict__ Wv,
                          float* __restrict__ MkP, float* __restrict__ MvP) {
  int idx = pidx, bi = 0;
  while (idx >= 8 - bi) { idx -= 8 - bi; ++bi; }
  int bj = bi + idx;
  int sel = zy & 1, kchunk = zy >> 1;
  const float* A = sel ? Wv : Wk;
  float* outP = (sel ? MvP : MkP) + kchunk * 65536;
  int w = t >> 6, l = t & 63, r16 = l & 15, ksub = l >> 4;
  __shared__ float red_a[4][32][33];

  int k0 = kchunk * 512 + w * 128;
  const float* ar0 = A + (size_t)(bi * 32 + r16) * NHD + k0;
  const float* ar1 = ar0 + 16 * NHD;
  const float* br0 = A + (size_t)(bj * 32 + r16) * NHD + k0;
  const float* br1 = br0 + 16 * NHD;

  bf8v ah[2][4], al[2][4], bh[2][4], bl[2][4];
#pragma unroll
  for (int kk = 0; kk < 4; ++kk) {
    int c0 = kk * 32 + ksub * 8;
    split8(*(const float4*)(ar0 + c0), *(const float4*)(ar0 + c0 + 4), ah[0][kk], al[0][kk]);
    split8(*(const float4*)(ar1 + c0), *(const float4*)(ar1 + c0 + 4), ah[1][kk], al[1][kk]);
    split8(*(const float4*)(br0 + c0), *(const float4*)(br0 + c0 + 4), bh[0][kk], bl[0][kk]);
    split8(*(const float4*)(br1 + c0), *(const float4*)(br1 + c0 + 4), bh[1][kk], bl[1][kk]);
  }
  f32x4 acc[2][2];
#pragma unroll
  for (int gi = 0; gi < 2; ++gi)
#pragma unroll
    for (int gj = 0; gj < 2; ++gj) acc[gi][gj] = (f32x4){0.f, 0.f, 0.f, 0.f};
#pragma unroll
  for (int kk = 0; kk < 4; ++kk) {
#pragma unroll
    for (int gi = 0; gi < 2; ++gi)
#pragma unroll
      for (int gj = 0; gj < 2; ++gj) {
        acc[gi][gj] = __builtin_amdgcn_mfma_f32_16x16x32_bf16(ah[gi][kk], bh[gj][kk], acc[gi][gj], 0, 0, 0);
        acc[gi][gj] = __builtin_amdgcn_mfma_f32_16x16x32_bf16(al[gi][kk], bh[gj][kk], acc[gi][gj], 0, 0, 0);
        acc[gi][gj] = __builtin_amdgcn_mfma_f32_16x16x32_bf16(ah[gi][kk], bl[gj][kk], acc[gi][gj], 0, 0, 0);
      }
  }
#pragma unroll
  for (int gi = 0; gi < 2; ++gi)
#pragma unroll
    for (int gj = 0; gj < 2; ++gj)
#pragma unroll
      for (int q = 0; q < 4; ++q)
        red_a[w][gi * 16 + ksub * 4 + q][gj * 16 + r16] = acc[gi][gj][q];
  __syncthreads();
  int r = t >> 3, c0 = (t & 7) * 4;
#pragma unroll
  for (int c = c0; c < c0 + 4; ++c) {
    float s = (red_a[0][r][c] + red_a[1][r][c]) + (red_a[2][r][c] + red_a[3][r][c]);
    outP[(size_t)(bi * 32 + r) * 256 + bj * 32 + c] = s;
  }
  if (bi != bj) {
#pragma unroll
    for (int c = c0; c < c0 + 4; ++c) {
      float s = (red_a[0][c][r] + red_a[1][c][r]) + (red_a[2][c][r] + red_a[3][c][r]);
      outP[(size_t)(bj * 32 + r) * 256 + bi * 32 + c] = s;
    }
  }
}

__device__ void aatred_body(int x, int sel, int t,
                            const float* __restrict__ MkP, const float* __restrict__ MvP,
                            short* __restrict__ Mkb, short* __restrict__ Mvb) {
  const float* P = sel ? MvP : MkP;
  short* O = sel ? Mvb : Mkb;
  int idx = x * 256 + t;
  float s = (P[idx] + P[65536 + idx] + P[131072 + idx] + P[196608 + idx]) * (1.0f / NHD);
  O[idx] = f2bf(s);
}

// wkeff: 4 batches per block (Wk traffic /4)
__device__ void wkeff_body(int h, int bg, int t,
                           const float* __restrict__ qraw, const float* __restrict__ qpart,
                           const float* __restrict__ gq, const float* __restrict__ betq,
                           const float* __restrict__ Wk, const float* __restrict__ bk,
                           const float* __restrict__ gk, const float* __restrict__ betk,
                           float* __restrict__ wkeff, float* __restrict__ cbGT) {
  __shared__ float qg[4][256];
  __shared__ float red_w[256];
  int b0 = bg * 4;
  int j = h * 256 + t;
  float cbv[4], Gv[4], Tv[4];
#pragma unroll
  for (int bi = 0; bi < 4; ++bi) {
    int b = b0 + bi;
    float s1 = 0.f, s2 = 0.f;
#pragma unroll
    for (int i = 0; i < 8; ++i) { s1 += qpart[(b * 8 + i) * 2]; s2 += qpart[(b * 8 + i) * 2 + 1]; }
    float m = s1 * (1.0f / NHD);
    float var = s2 * (1.0f / NHD) - m * m;
    float is = 1.0f / sqrtf(var + EPS);
    float q = (qraw[(size_t)b * NHD + j] - m) * is * gq[j] + betq[j];
    float qgv = q * gk[j];
    qg[bi][t] = qgv;
    cbv[bi] = block_reduce_sum(bk[j] * qgv, red_w, t);
    Gv[bi] = block_reduce_sum(qgv, red_w, t);
    Tv[bi] = block_reduce_sum(q * betk[j], red_w, t);
  }
  float acc[4] = {0.f, 0.f, 0.f, 0.f};
  const float4* wr = (const float4*)(Wk + (size_t)t * NHD + h * 256);
#pragma unroll 2
  for (int d4 = 0; d4 < 64; ++d4) {
    float4 w = wr[d4];
#pragma unroll
    for (int bi = 0; bi < 4; ++bi) {
      acc[bi] += w.x * qg[bi][d4 * 4] + w.y * qg[bi][d4 * 4 + 1]
               + w.z * qg[bi][d4 * 4 + 2] + w.w * qg[bi][d4 * 4 + 3];
    }
  }
#pragma unroll
  for (int bi = 0; bi < 4; ++bi) {
    int b = b0 + bi;
    wkeff[(size_t)(b * NH + h) * ND + t] = acc[bi];
    if (t == 0) { float* p = cbGT + (b * NH + h) * 4; p[0] = cbv[bi]; p[1] = Gv[bi]; p[2] = Tv[bi]; }
  }
}

// ================= merged launchers =================

// kA: blocks [0,512) meta | [512,768) q1 (8h x 32bg) | [768,1056) aat2
__global__ __launch_bounds__(256) void kA(const float* __restrict__ Wk,
                                          const float* __restrict__ bk,
                                          const float* __restrict__ Wv,
                                          const float* __restrict__ bv,
                                          const int* __restrict__ mask_i,
                                          const float* __restrict__ local,
                                          const float* __restrict__ Wq,
                                          const float* __restrict__ bq,
                                          float* __restrict__ kmeta,
                                          float* __restrict__ vmeta,
                                          int* __restrict__ flag,
                                          float* __restrict__ qraw,
                                          float* __restrict__ qpart,
                                          float* __restrict__ MkP,
                                          float* __restrict__ MvP) {
  int bid = blockIdx.x, t = threadIdx.x;
  if (bid < 512) {
    meta_body(bid & 255, bid >> 8, t, Wk, bk, Wv, bv, mask_i, kmeta, vmeta, flag);
  } else if (bid < 768) {
    int id = bid - 512;
    q1_body(id & 7, id >> 3, t, local, Wq, bq, qraw, qpart);
  } else {
    int id = bid - 768;
    aat2_body(id % 36, id / 36, t, Wk, Wv, MkP, MvP);
  }
}

// kB: blocks [0,512) aat_reduce | [512,768) wkeff (8h x 32bg)
__global__ __launch_bounds__(256) void kB(const float* __restrict__ MkP,
                                          const float* __restrict__ MvP,
                                          short* __restrict__ Mkb,
                                          short* __restrict__ Mvb,
                                          const float* __restrict__ qraw,
                                          const float* __restrict__ qpart,
                                          const float* __restrict__ gq,
                                          const float* __restrict__ betq,
                                          const float* __restrict__ Wk,
                                          const float* __restrict__ bk,
                                          const float* __restrict__ gk,
                                          const float* __restrict__ betk,
                                          float* __restrict__ wkeff,
                                          float* __restrict__ cbGT) {
  int bid = blockIdx.x, t = threadIdx.x;
  if (bid < 512) {
    aatred_body(bid & 255, bid >> 8, t, MkP, MvP, Mkb, Mvb);
  } else {
    int id = bid - 512;
    wkeff_body(id & 7, id >> 3, t, qraw, qpart, gq, betq, Wk, bk, gk, betk, wkeff, cbGT);
  }
}

// ---------- K5a (MFMA): LN moments, symmetry-reduced, VALU step-2, NO LDS (r13 best) ----------
// Per-kernel A/B across sessions: this body 44.5-47.6us vs LDS-staged 49-51us.
// No __shared__, no barriers; waves fully independent. Step-2 re-reads X at the
// MFMA D-layout positions (L1/L2-hot); FETCH ~63MB is L3-absorbed.
__global__ __launch_bounds__(256) void k_moments(const float* __restrict__ dist,
                                                 const float* __restrict__ sites,
                                                 const short* __restrict__ Mkb,
                                                 const short* __restrict__ Mvb,
                                                 const float* __restrict__ kmeta,
                                                 const float* __restrict__ vmeta,
                                                 float* __restrict__ mk_arr,
                                                 float* __restrict__ sk_arr,
                                                 float* __restrict__ mv_arr,
                                                 float* __restrict__ sv_arr) {
  int sel = blockIdx.y;
  const float* X = sel ? sites : dist;
  const short* Mb = sel ? Mvb : Mkb;
  const float* meta = sel ? vmeta : kmeta;
  float* m_out = sel ? mv_arr : mk_arr;
  float* s_out = sel ? sv_arr : sk_arr;

  int t = threadIdx.x;
  int w = t >> 6;
  int l = t & 63;
  int r16 = l & 15;
  int ksub = l >> 4;

  size_t rowA = (size_t)blockIdx.x * 128 + w * 32;
  const float* xr0 = X + (rowA + r16) * 256;
  const float* xr1 = xr0 + 16 * 256;

  bf8v af0[8], af1[8];
  float pm0 = 0.f, pl0 = 0.f, pm1 = 0.f, pl1 = 0.f;
#pragma unroll
  for (int kc = 0; kc < 8; ++kc) {
    int c0 = kc * 32 + ksub * 8;
    float4 wa = *(const float4*)(meta + c0);
    float4 wb = *(const float4*)(meta + c0 + 4);
    float4 la = *(const float4*)(meta + 256 + c0);
    float4 lb = *(const float4*)(meta + 256 + c0 + 4);
    float4 x0a = *(const float4*)(xr0 + c0);
    float4 x0b = *(const float4*)(xr0 + c0 + 4);
    float4 x1a = *(const float4*)(xr1 + c0);
    float4 x1b = *(const float4*)(xr1 + c0 + 4);
    pm0 += x0a.x * wa.x + x0a.y * wa.y + x0a.z * wa.z + x0a.w * wa.w
         + x0b.x * wb.x + x0b.y * wb.y + x0b.z * wb.z + x0b.w * wb.w;
    pl0 += x0a.x * la.x + x0a.y * la.y + x0a.z * la.z + x0a.w * la.w
         + x0b.x * lb.x + x0b.y * lb.y + x0b.z * lb.z + x0b.w * lb.w;
    pm1 += x1a.x * wa.x + x1a.y * wa.y + x1a.z * wa.z + x1a.w * wa.w
         + x1b.x * wb.x + x1b.y * wb.y + x1b.z * wb.z + x1b.w * wb.w;
    pl1 += x1a.x * la.x + x1a.y * la.y + x1a.z * la.z + x1a.w * la.w
         + x1b.x * lb.x + x1b.y * lb.y + x1b.z * lb.z + x1b.w * lb.w;
    bf8v a0, a1;
    a0[0] = f2bf(x0a.x); a0[1] = f2bf(x0a.y); a0[2] = f2bf(x0a.z); a0[3] = f2bf(x0a.w);
    a0[4] = f2bf(x0b.x); a0[5] = f2bf(x0b.y); a0[6] = f2bf(x0b.z); a0[7] = f2bf(x0b.w);
    a1[0] = f2bf(x1a.x); a1[1] = f2bf(x1a.y); a1[2] = f2bf(x1a.z); a1[3] = f2bf(x1a.w);
    a1[4] = f2bf(x1b.x); a1[5] = f2bf(x1b.y); a1[6] = f2bf(x1b.z); a1[7] = f2bf(x1b.w);
    af0[kc] = a0;
    af1[kc] = a1;
  }
  pm0 += __shfl_xor(pm0, 16); pm0 += __shfl_xor(pm0, 32);
  pl0 += __shfl_xor(pl0, 16); pl0 += __shfl_xor(pl0, 32);
  pm1 += __shfl_xor(pm1, 16); pm1 += __shfl_xor(pm1, 32);
  pl1 += __shfl_xor(pl1, 16); pl1 += __shfl_xor(pl1, 32);

  f32x4 yv0 = {0.f, 0.f, 0.f, 0.f}, yv1 = {0.f, 0.f, 0.f, 0.f};
  const float* xb0 = X + rowA * 256;
  const float* xb1 = X + (rowA + 16) * 256;

#pragma unroll
  for (int n = 0; n < 16; ++n) {
    const int kcd = n >> 1;
    f32x4 ta = {0.f, 0.f, 0.f, 0.f}, tb = {0.f, 0.f, 0.f, 0.f};
#pragma unroll
    for (int kc = 0; kc < kcd; ++kc) {
      bf8v bfv = *(const bf8v*)(Mb + ((size_t)(n * 16 + r16) << 8) + kc * 32 + ksub * 8);
      ta = __builtin_amdgcn_mfma_f32_16x16x32_bf16(af0[kc], bfv, ta, 0, 0, 0);
      tb = __builtin_amdgcn_mfma_f32_16x16x32_bf16(af1[kc], bfv, tb, 0, 0, 0);
    }
    ta = ta + ta;      // double strictly-upper contributions (M symmetric)
    tb = tb + tb;
    {
      bf8v bfd = *(const bf8v*)(Mb + ((size_t)(n * 16 + r16) << 8) + kcd * 32 + ksub * 8);
      ta = __builtin_amdgcn_mfma_f32_16x16x32_bf16(af0[kcd], bfd, ta, 0, 0, 0);
      tb = __builtin_amdgcn_mfma_f32_16x16x32_bf16(af1[kcd], bfd, tb, 0, 0, 0);
    }
#pragma unroll
    for (int q = 0; q < 4; ++q) {
      float xv0 = xb0[(size_t)(ksub * 4 + q) * 256 + n * 16 + r16];
      float xv1 = xb1[(size_t)(ksub * 4 + q) * 256 + n * 16 + r16];
      yv0[q] = fmaf(ta[q], xv0, yv0[q]);
      yv1[q] = fmaf(tb[q], xv1, yv1[q]);
    }
  }

#pragma unroll
  for (int off = 1; off < 16; off <<= 1) {
#pragma unroll
    for (int q = 0; q < 4; ++q) {
      yv0[q] += __shfl_xor(yv0[q], off);
      yv1[q] += __shfl_xor(yv1[q], off);
    }
  }

  int qs = r16 & 3;
  float yd0 = (qs == 0) ? yv0[0] : (qs == 1) ? yv0[1] : (qs == 2) ? yv0[2] : yv0[3];
  float yd1 = (qs == 0) ? yv1[0] : (qs == 1) ? yv1[1] : (qs == 2) ? yv1[2] : yv1[3];
  float bbar = meta[512], cc = meta[513];
  if (ksub == (r16 >> 2)) {
    float m0 = pm0 + bbar;
    float var0 = fmaxf(yd0 + (pl0 + cc) - m0 * m0, 0.0f) + EPS;
    m_out[rowA + r16] = m0;
    s_out[rowA + r16] = 1.0f / sqrtf(var0);
    float m1 = pm1 + bbar;
    float var1 = fmaxf(yd1 + (pl1 + cc) - m1 * m1, 0.0f) + EPS;
    m_out[rowA + 16 + r16] = m1;
    s_out[rowA + 16 + r16] = 1.0f / sqrtf(var1);
  }
}

// ---------- K5 (MFMA): fused scores + softmax + PV, one block per b ----------
__global__ __launch_bounds__(512) void k_attn2(const float* __restrict__ dist,
                                               const float* __restrict__ sites,
                                               const int* __restrict__ mask_i,
                                               const int* __restrict__ mflag,
                                               const float* __restrict__ wkeff,
                                               const float* __restrict__ cbGT,
                                               const float* __restrict__ mk_arr,
                                               const float* __restrict__ sk_arr,
                                               const float* __restrict__ mv_arr,
                                               const float* __restrict__ sv_arr,
                                               float* __restrict__ zbuf,
                                               float* __restrict__ bg) {
  int b = blockIdx.x, t = threadIdx.x;
  int w = t >> 6, l = t & 63, r16 = l & 15, ksub = l >> 4;

  __shared__ float us[16][260];
  __shared__ __align__(16) short St[256][72];

  for (int i = t; i < 8 * 260; i += 512) (&us[8][0])[i] = 0.f;

  const int mbytes = mflag[0];

  const float* xr0 = dist + ((size_t)b * NS + w * 32 + r16) * ND;
  const float* xr1 = xr0 + 16 * ND;
  const float* wkp = wkeff + ((size_t)b * NH + (r16 & 7)) * ND;
  f32x4 u0 = {0.f, 0.f, 0.f, 0.f}, u1 = {0.f, 0.f, 0.f, 0.f};
#pragma unroll 2
  for (int kc = 0; kc < 8; ++kc) {
    int c0 = kc * 32 + ksub * 8;
    float4 xa = *(const float4*)(xr0 + c0);
    float4 xb = *(const float4*)(xr0 + c0 + 4);
    float4 ya = *(const float4*)(xr1 + c0);
    float4 yb = *(const float4*)(xr1 + c0 + 4);
    float4 wa = {0.f, 0.f, 0.f, 0.f}, wb = {0.f, 0.f, 0.f, 0.f};
    if (r16 < 8) { wa = *(const float4*)(wkp + c0); wb = *(const float4*)(wkp + c0 + 4); }
    bf8v xh, xl, yh, yl, wh, wl;
    split8(xa, xb, xh, xl);
    split8(ya, yb, yh, yl);
    split8(wa, wb, wh, wl);
    u0 = __builtin_amdgcn_mfma_f32_16x16x32_bf16(xh, wh, u0, 0, 0, 0);
    u0 = __builtin_amdgcn_mfma_f32_16x16x32_bf16(xl, wh, u0, 0, 0, 0);
    u0 = __builtin_amdgcn_mfma_f32_16x16x32_bf16(xh, wl, u0, 0, 0, 0);
    u1 = __builtin_amdgcn_mfma_f32_16x16x32_bf16(yh, wh, u1, 0, 0, 0);
    u1 = __builtin_amdgcn_mfma_f32_16x16x32_bf16(yl, wh, u1, 0, 0, 0);
    u1 = __builtin_amdgcn_mfma_f32_16x16x32_bf16(yh, wl, u1, 0, 0, 0);
  }

  float cb = 0.f, G = 0.f, T = 0.f;
  if (r16 < 8) { const float* p = cbGT + (b * NH + r16) * 4; cb = p[0]; G = p[1]; T = p[2]; }
  const unsigned char* mask_b = (const unsigned char*)mask_i;
#pragma unroll
  for (int g = 0; g < 2; ++g) {
    f32x4 uu = g ? u1 : u0;
    int base = w * 32 + g * 16 + ksub * 4;
    float4 mk4 = *(const float4*)(mk_arr + b * NS + base);
    float4 sk4 = *(const float4*)(sk_arr + b * NS + base);
    int mm[4];
    if (mbytes) {
      mm[0] = mask_b[b * NS + base];     mm[1] = mask_b[b * NS + base + 1];
      mm[2] = mask_b[b * NS + base + 2]; mm[3] = mask_b[b * NS + base + 3];
    } else {
      mm[0] = mask_i[b * NS + base];     mm[1] = mask_i[b * NS + base + 1];
      mm[2] = mask_i[b * NS + base + 2]; mm[3] = mask_i[b * NS + base + 3];
    }
    const float* mkp = (const float*)&mk4;
    const float* skp = (const float*)&sk4;
#pragma unroll
    for (int q = 0; q < 4; ++q) {
      float u = ((uu[q] + cb - mkp[q] * G) * skp[q] + T) * 0.0625f;
      if (mm[q]) u = -1e30f;
      if (r16 < 8) us[r16][base + q] = u;
    }
  }
  __syncthreads();

  {
    int h = w;
    float v[4];
#pragma unroll
    for (int i = 0; i < 4; ++i) v[i] = us[h][l + 64 * i];
    float mx = fmaxf(fmaxf(v[0], v[1]), fmaxf(v[2], v[3]));
    for (int off = 32; off > 0; off >>= 1) mx = fmaxf(mx, __shfl_xor(mx, off));
    float sum = 0.f;
#pragma unroll
    for (int i = 0; i < 4; ++i) { v[i] = expf(v[i] - mx); sum += v[i]; }
    for (int off = 32; off > 0; off >>= 1) sum += __shfl_xor(sum, off);
    float inv = 1.0f / sum;
    float bp = 0.f, gp = 0.f;
#pragma unroll
    for (int i = 0; i < 4; ++i) {
      int s = l + 64 * i;
      float a = v[i] * inv;
      float sv = sv_arr[b * NS + s];
      float mv = mv_arr[b * NS + s];
      float wv = a * sv;
      us[h][s] = wv;
      bp += wv;
      gp += wv * mv;
    }
    for (int off = 32; off > 0; off >>= 1) { bp += __shfl_xor(bp, off); gp += __shfl_xor(gp, off); }
    if (l == 0) { float* p = bg + (b * NH + h) * 2; p[0] = bp; p[1] = gp; }
  }
  __syncthreads();

  f32x4 z0 = {0.f, 0.f, 0.f, 0.f}, z1 = {0.f, 0.f, 0.f, 0.f};
  int half = t >> 8, tc = t & 255;
  for (int chunk = 0; chunk < 4; ++chunk) {
    const float* Sp = sites + ((size_t)b * NS + chunk * 64) * ND + tc;
#pragma unroll
    for (int it = 0; it < 4; ++it) {
      int s8 = (half * 4 + it) * 8;
      bf8v vtmp;
#pragma unroll
      for (int j = 0; j < 8; ++j) vtmp[j] = f2bf(Sp[(size_t)(s8 + j) * ND]);
      *(bf8v*)&St[tc][s8] = vtmp;
    }
    __syncthreads();
#pragma unroll
    for (int kst = 0; kst < 2; ++kst) {
      int sg = chunk * 64 + kst * 32 + ksub * 8;
      int sl0 = kst * 32 + ksub * 8;
      float4 p0 = *(const float4*)&us[r16][sg];
      float4 p1 = *(const float4*)&us[r16][sg + 4];
      bf8v ah, al;
      split8(p0, p1, ah, al);
      bf8v b0 = *(const bf8v*)&St[(2 * w) * 16 + r16][sl0];
      bf8v b1 = *(const bf8v*)&St[(2 * w + 1) * 16 + r16][sl0];
      z0 = __builtin_amdgcn_mfma_f32_16x16x32_bf16(ah, b0, z0, 0, 0, 0);
      z0 = __builtin_amdgcn_mfma_f32_16x16x32_bf16(al, b0, z0, 0, 0, 0);
      z1 = __builtin_amdgcn_mfma_f32_16x16x32_bf16(ah, b1, z1, 0, 0, 0);
      z1 = __builtin_amdgcn_mfma_f32_16x16x32_bf16(al, b1, z1, 0, 0, 0);
    }
    __syncthreads();
  }
  if (ksub < 2) {
#pragma unroll
    for (int q = 0; q < 4; ++q) {
      int h = ksub * 4 + q;
      zbuf[((size_t)b * NH + h) * ND + 2 * w * 16 + r16] = z0[q];
      zbuf[((size_t)b * NH + h) * ND + (2 * w + 1) * 16 + r16] = z1[q];
    }
  }
}

// ---------- K6a: o = z@Wv + corrections + residual, 4 batches/block (Wv traffic /4) ----------
__global__ __launch_bounds__(256) void k_o1(const float* __restrict__ zbuf,
                                            const float* __restrict__ bg,
                                            const float* __restrict__ qraw,
                                            const float* __restrict__ qpart,
                                            const float* __restrict__ gq,
                                            const float* __restrict__ betq,
                                            const float* __restrict__ Wv,
                                            const float* __restrict__ bv,
                                            const float* __restrict__ gv,
                                            const float* __restrict__ betv,
                                            float* __restrict__ o_buf,
                                            float* __restrict__ part1) {
  int h = blockIdx.x, bg4 = blockIdx.y, t = threadIdx.x;
  __shared__ float zs[4][256];
  __shared__ float red[256];
  int b0 = bg4 * 4;
#pragma unroll
  for (int bi = 0; bi < 4; ++bi)
    zs[bi][t] = zbuf[((size_t)(b0 + bi) * NH + h) * ND + t];
  __syncthreads();
  int j = h * 256 + t;
  float acc[4] = {0.f, 0.f, 0.f, 0.f};
  const float* W = Wv + j;
  for (int c = 0; c < 256; ++c) {
    float wv = W[(size_t)c * NHD];
#pragma unroll
    for (int bi = 0; bi < 4; ++bi) acc[bi] = fmaf(zs[bi][c], wv, acc[bi]);
  }
#pragma unroll
  for (int bi = 0; bi < 4; ++bi) {
    int b = b0 + bi;
    float qs1 = 0.f, qs2 = 0.f;
#pragma unroll
    for (int i = 0; i < 8; ++i) { qs1 += qpart[(b * 8 + i) * 2]; qs2 += qpart[(b * 8 + i) * 2 + 1]; }
    float qm = qs1 * (1.0f / NHD);
    float qvar = qs2 * (1.0f / NHD) - qm * qm;
    float qis = 1.0f / sqrtf(qvar + EPS);
    float bets = bg[(b * NH + h) * 2], gams = bg[(b * NH + h) * 2 + 1];
    float qln = (qraw[(size_t)b * NHD + j] - qm) * qis * gq[j] + betq[j];
    float o = gv[j] * (acc[bi] + bv[j] * bets - gams) + betv[j] + qln;
    o_buf[(size_t)b * NHD + j] = o;
    float s1 = block_reduce_sum(o, red, t);
    float s2 = block_reduce_sum(o * o, red, t);
    if (t == 0) { part1[(b * 8 + h) * 2] = s1; part1[(b * 8 + h) * 2 + 1] = s2; }
  }
}

// ---------- K6b: y1 = LN1(o); split-K partials of y1@Wo, 4 batches/block ----------
__global__ __launch_bounds__(256) void k_o2(const float* __restrict__ o_buf,
                                            const float* __restrict__ part1,
                                            const float* __restrict__ g1,
                                            const float* __restrict__ b1,
                                            const float* __restrict__ Wo,
                                            float* __restrict__ part2) {
  int ks = blockIdx.x, bg4 = blockIdx.y, t = threadIdx.x;
  __shared__ float y1s[4][256];
  int b0 = bg4 * 4;
  int jj = ks * 256 + t;
#pragma unroll
  for (int bi = 0; bi < 4; ++bi) {
    int b = b0 + bi;
    float s1 = 0.f, s2 = 0.f;
#pragma unroll
    for (int i = 0; i < 8; ++i) { s1 += part1[(b * 8 + i) * 2]; s2 += part1[(b * 8 + i) * 2 + 1]; }
    float m = s1 * (1.0f / NHD);
    float var = s2 * (1.0f / NHD) - m * m;
    float is = 1.0f / sqrtf(var + EPS);
    y1s[bi][t] = (o_buf[(size_t)b * NHD + jj] - m) * is * g1[jj] + b1[jj];
  }
  __syncthreads();
  float acc[4] = {0.f, 0.f, 0.f, 0.f};
  const float* W = Wo + (size_t)ks * 256 * 256 + t;
  for (int i = 0; i < 256; ++i) {
    float wv = W[(size_t)i * 256];
#pragma unroll
    for (int bi = 0; bi < 4; ++bi) acc[bi] = fmaf(y1s[bi][i], wv, acc[bi]);
  }
#pragma unroll
  for (int bi = 0; bi < 4; ++bi)
    part2[((size_t)ks * NB + b0 + bi) * 256 + t] = acc[bi];
}

// ---------- K6c: reduce split-K, bias, LN2, write outputs ----------
__global__ __launch_bounds__(256) void k_o3(const float* __restrict__ part2,
                                            const float* __restrict__ bo,
                                            const float* __restrict__ g2,
                                            const float* __restrict__ b2,
                                            const float* __restrict__ beta_a,
                                            float* __restrict__ out) {
  int b = blockIdx.x, t = threadIdx.x;
  __shared__ float red[256];
  float acc = bo[t];
#pragma unroll
  for (int ks = 0; ks < 8; ++ks) acc += part2[((size_t)ks * NB + b) * 256 + t];
  float q1 = block_reduce_sum(acc, red, t);
  float q2 = block_reduce_sum(acc * acc, red, t);
  float m2 = q1 * (1.0f / 256.0f);
  float v2 = q2 * (1.0f / 256.0f) - m2 * m2;
  float is2 = 1.0f / sqrtf(v2 + EPS);
  out[NB * NS + b * 256 + t] = (acc - m2) * is2 * g2[t] + b2[t];
  out[b * 256 + t] = beta_a[0];
}

extern "C" void kernel_launch(void* const* d_in, const int* in_sizes, int n_in,
                              void* d_out, int out_size, void* d_ws, size_t ws_size,
                              hipStream_t stream) {
  (void)in_sizes; (void)n_in; (void)out_size; (void)ws_size;
  const float* local = (const float*)d_in[0];
  const float* dist  = (const float*)d_in[1];
  const float* sites = (const float*)d_in[2];
  const int*   mask  = (const int*)d_in[3];
  const float* Wq   = (const float*)d_in[4];
  const float* bq   = (const float*)d_in[5];
  const float* gq   = (const float*)d_in[6];
  const float* betq = (const float*)d_in[7];
  const float* Wk   = (const float*)d_in[8];
  const float* bk   = (const float*)d_in[9];
  const float* gk   = (const float*)d_in[10];
  const float* betk = (const float*)d_in[11];
  const float* Wv   = (const float*)d_in[12];
  const float* bv   = (const float*)d_in[13];
  const float* gv   = (const float*)d_in[14];
  const float* betv = (const float*)d_in[15];
  const float* g1   = (const float*)d_in[16];
  const float* b1   = (const float*)d_in[17];
  const float* Wo   = (const float*)d_in[18];
  const float* bo   = (const float*)d_in[19];
  const float* g2   = (const float*)d_in[20];
  const float* b2   = (const float*)d_in[21];
  const float* beta_a = (const float*)d_in[25];
  float* out = (float*)d_out;

  float* ws = (float*)d_ws;
  float* MkP   = ws;                // 262144
  float* MvP   = MkP + 262144;      // 262144 (later aliased: part2)
  short* Mkb   = (short*)(MvP + 262144);   // 65536 shorts
  short* Mvb   = Mkb + 65536;              // 65536 shorts
  float* kmeta = (float*)(Mvb + 65536);    // 1024
  float* vmeta = kmeta + 1024;      // 1024
  float* qraw  = vmeta + 1024;      // 262144 (also written as o_buf by k_o1)
  float* wkeff = qraw + 262144;     // 262144
  float* cbGT  = wkeff + 262144;    // 4096
  float* mk_arr = cbGT + 4096;      // 32768
  float* sk_arr = mk_arr + 32768;   // 32768
  float* mv_arr = sk_arr + 32768;   // 32768
  float* sv_arr = mv_arr + 32768;   // 32768
  float* zbuf  = sv_arr + 32768;    // 262144
  float* bg    = zbuf + 262144;     // 2048
  int*   mflag = (int*)(bg + 2048); // 16 ints
  float* part1 = (float*)(mflag + 16); // 2048
  float* qpart = part1 + 2048;      // 2048

  float* o_buf = qraw;   // k_o1 thread-local read-then-write, safe alias
  float* part2 = MvP;    // live k_o2..k_o3 (MvP dead after kB)

  kA<<<dim3(1056), dim3(256), 0, stream>>>(Wk, bk, Wv, bv, mask, local, Wq, bq,
                                           kmeta, vmeta, mflag, qraw, qpart, MkP, MvP);
  kB<<<dim3(768), dim3(256), 0, stream>>>(MkP, MvP, Mkb, Mvb, qraw, qpart, gq, betq,
                                          Wk, bk, gk, betk, wkeff, cbGT);
  k_moments<<<dim3(256, 2), dim3(256), 0, stream>>>(dist, sites, Mkb, Mvb, kmeta, vmeta,
                                                    mk_arr, sk_arr, mv_arr, sv_arr);
  k_attn2<<<dim3(128), dim3(512), 0, stream>>>(dist, sites, mask, mflag, wkeff, cbGT,
                                               mk_arr, sk_arr, mv_arr, sv_arr, zbuf, bg);
  k_o1<<<dim3(8, 32), dim3(256), 0, stream>>>(zbuf, bg, qraw, qpart, gq, betq,
                                              Wv, bv, gv, betv, o_buf, part1);
  k_o2<<<dim3(8, 32), dim3(256), 0, stream>>>(o_buf, part1, g1, b1, Wo, part2);
  k_o3<<<dim3(128), dim3(256), 0, stream>>>(part2, bo, g2, b2, beta_a, out);
}

// Round 18
// 128.639 us; speedup vs baseline: 1.0720x; 1.0720x over previous
//
#include <hip/hip_runtime.h>

#define NB 128
#define NS 256
#define ND 256
#define NH 8
#define NHD 2048
static constexpr float EPS = 1e-5f;

typedef __attribute__((ext_vector_type(8))) short bf8v;
typedef __attribute__((ext_vector_type(4))) float f32x4;

__device__ __forceinline__ short f2bf(float f) {
  unsigned u = __float_as_uint(f);
  unsigned r = (u + 0x7fffu + ((u >> 16) & 1u)) >> 16;
  return (short)r;
}

__device__ __forceinline__ void split8(float4 a, float4 b, bf8v& hi, bf8v& lo) {
  float x[8] = {a.x, a.y, a.z, a.w, b.x, b.y, b.z, b.w};
  bf8v h, l;
#pragma unroll
  for (int i = 0; i < 8; ++i) {
    unsigned u = __float_as_uint(x[i]);
    unsigned hb = (u + 0x7fffu + ((u >> 16) & 1u)) >> 16;
    h[i] = (short)hb;
    float hf = __uint_as_float(hb << 16);
    l[i] = f2bf(x[i] - hf);
  }
  hi = h;
  lo = l;
}

__device__ __forceinline__ float block_reduce_sum(float v, float* red, int t) {
  __syncthreads();
  red[t] = v;
  __syncthreads();
  for (int off = 128; off > 0; off >>= 1) {
    if (t < off) red[t] += red[t + off];
    __syncthreads();
  }
  return red[0];
}

// ================= device bodies =================

__device__ void meta_body(int c, int sel, int t,
                          const float* __restrict__ Wk, const float* __restrict__ bk,
                          const float* __restrict__ Wv, const float* __restrict__ bv,
                          const int* __restrict__ mask_i,
                          float* __restrict__ kmeta, float* __restrict__ vmeta,
                          int* __restrict__ flag) {
  const float* W = sel ? Wv : Wk;
  const float* bvec = sel ? bv : bk;
  float* meta = sel ? vmeta : kmeta;
  __shared__ float red_m[256];
  __shared__ int sflag;
  float s_w = 0.f, s_l = 0.f;
  const float* row = W + (size_t)c * NHD;
  for (int j = t; j < NHD; j += 256) { float w = row[j]; s_w += w; s_l += w * bvec[j]; }
  s_w = block_reduce_sum(s_w, red_m, t);
  s_l = block_reduce_sum(s_l, red_m, t);
  if (t == 0) { meta[c] = s_w * (1.0f / NHD); meta[256 + c] = s_l * (2.0f / NHD); }
  if (c == 0) {
    float s_b = 0.f, s_b2 = 0.f;
    for (int j = t; j < NHD; j += 256) { float bb = bvec[j]; s_b += bb; s_b2 += bb * bb; }
    s_b = block_reduce_sum(s_b, red_m, t);
    s_b2 = block_reduce_sum(s_b2, red_m, t);
    if (t == 0) { meta[512] = s_b * (1.0f / NHD); meta[513] = s_b2 * (1.0f / NHD); }
  }
  if (c == 1 && sel == 0) {
    if (t == 0) sflag = 0;
    __syncthreads();
    int any = 0;
    for (int i = t; i < 8192; i += 256) {
      unsigned v = (unsigned)mask_i[i];
      if (v > 1u) any = 1;
    }
    if (any) atomicOr(&sflag, 1);
    __syncthreads();
    if (t == 0) flag[0] = sflag;
  }
}

// q1: 4 batches per block; each Wq element feeds 4 FMAs (weight traffic /4)
__device__ void q1_body(int h, int bg, int t,
                        const float* __restrict__ local, const float* __restrict__ Wq,
                        const float* __restrict__ bq,
                        float* __restrict__ qraw, float* __restrict__ qpart) {
  __shared__ float ls[4][256];
  __shared__ float red_q[256];
  int b0 = bg * 4;
#pragma unroll
  for (int bi = 0; bi < 4; ++bi) ls[bi][t] = local[(b0 + bi) * ND + t];
  __syncthreads();
  int j = h * 256 + t;
  float acc[4] = {0.f, 0.f, 0.f, 0.f};
  const float* W = Wq + j;
  for (int c = 0; c < 256; ++c) {
    float wv = W[(size_t)c * NHD];
#pragma unroll
    for (int bi = 0; bi < 4; ++bi) acc[bi] = fmaf(ls[bi][c], wv, acc[bi]);
  }
#pragma unroll
  for (int bi = 0; bi < 4; ++bi) {
    int b = b0 + bi;
    float a = acc[bi] + bq[j];
    qraw[(size_t)b * NHD + j] = a;
    float s1 = block_reduce_sum(a, red_q, t);
    float s2 = block_reduce_sum(a * a, red_q, t);
    if (t == 0) { qpart[(b * 8 + h) * 2] = s1; qpart[(b * 8 + h) * 2 + 1] = s2; }
  }
}

__device__ void aat2_body(int pidx, int zy, int t,
                          const float* __restrict__ Wk, const float* __restrict__ Wv,
                          float* __restrict__ MkP, float* __restrict__ MvP) {
  int idx = pidx, bi = 0;
  while (idx >= 8 - bi) { idx -= 8 - bi; ++bi; }
  int bj = bi + idx;
  int sel = zy & 1, kchunk = zy >> 1;
  const float* A = sel ? Wv : Wk;
  float* outP = (sel ? MvP : MkP) + kchunk * 65536;
  int w = t >> 6, l = t & 63, r16 = l & 15, ksub = l >> 4;
  __shared__ float red_a[4][32][33];

  int k0 = kchunk * 512 + w * 128;
  const float* ar0 = A + (size_t)(bi * 32 + r16) * NHD + k0;
  const float* ar1 = ar0 + 16 * NHD;
  const float* br0 = A + (size_t)(bj * 32 + r16) * NHD + k0;
  const float* br1 = br0 + 16 * NHD;

  bf8v ah[2][4], al[2][4], bh[2][4], bl[2][4];
#pragma unroll
  for (int kk = 0; kk < 4; ++kk) {
    int c0 = kk * 32 + ksub * 8;
    split8(*(const float4*)(ar0 + c0), *(const float4*)(ar0 + c0 + 4), ah[0][kk], al[0][kk]);
    split8(*(const float4*)(ar1 + c0), *(const float4*)(ar1 + c0 + 4), ah[1][kk], al[1][kk]);
    split8(*(const float4*)(br0 + c0), *(const float4*)(br0 + c0 + 4), bh[0][kk], bl[0][kk]);
    split8(*(const float4*)(br1 + c0), *(const float4*)(br1 + c0 + 4), bh[1][kk], bl[1][kk]);
  }
  f32x4 acc[2][2];
#pragma unroll
  for (int gi = 0; gi < 2; ++gi)
#pragma unroll
    for (int gj = 0; gj < 2; ++gj) acc[gi][gj] = (f32x4){0.f, 0.f, 0.f, 0.f};
#pragma unroll
  for (int kk = 0; kk < 4; ++kk) {
#pragma unroll
    for (int gi = 0; gi < 2; ++gi)
#pragma unroll
      for (int gj = 0; gj < 2; ++gj) {
        acc[gi][gj] = __builtin_amdgcn_mfma_f32_16x16x32_bf16(ah[gi][kk], bh[gj][kk], acc[gi][gj], 0, 0, 0);
        acc[gi][gj] = __builtin_amdgcn_mfma_f32_16x16x32_bf16(al[gi][kk], bh[gj][kk], acc[gi][gj], 0, 0, 0);
        acc[gi][gj] = __builtin_amdgcn_mfma_f32_16x16x32_bf16(ah[gi][kk], bl[gj][kk], acc[gi][gj], 0, 0, 0);
      }
  }
#pragma unroll
  for (int gi = 0; gi < 2; ++gi)
#pragma unroll
    for (int gj = 0; gj < 2; ++gj)
#pragma unroll
      for (int q = 0; q < 4; ++q)
        red_a[w][gi * 16 + ksub * 4 + q][gj * 16 + r16] = acc[gi][gj][q];
  __syncthreads();
  int r = t >> 3, c0 = (t & 7) * 4;
#pragma unroll
  for (int c = c0; c < c0 + 4; ++c) {
    float s = (red_a[0][r][c] + red_a[1][r][c]) + (red_a[2][r][c] + red_a[3][r][c]);
    outP[(size_t)(bi * 32 + r) * 256 + bj * 32 + c] = s;
  }
  if (bi != bj) {
#pragma unroll
    for (int c = c0; c < c0 + 4; ++c) {
      float s = (red_a[0][c][r] + red_a[1][c][r]) + (red_a[2][c][r] + red_a[3][c][r]);
      outP[(size_t)(bj * 32 + r) * 256 + bi * 32 + c] = s;
    }
  }
}

__device__ void aatred_body(int x, int sel, int t,
                            const float* __restrict__ MkP, const float* __restrict__ MvP,
                            short* __restrict__ Mkb, short* __restrict__ Mvb) {
  const float* P = sel ? MvP : MkP;
  short* O = sel ? Mvb : Mkb;
  int idx = x * 256 + t;
  float s = (P[idx] + P[65536 + idx] + P[131072 + idx] + P[196608 + idx]) * (1.0f / NHD);
  O[idx] = f2bf(s);
}

// wkeff: 4 batches per block (Wk traffic /4)
__device__ void wkeff_body(int h, int bg, int t,
                           const float* __restrict__ qraw, const float* __restrict__ qpart,
                           const float* __restrict__ gq, const float* __restrict__ betq,
                           const float* __restrict__ Wk, const float* __restrict__ bk,
                           const float* __restrict__ gk, const float* __restrict__ betk,
                           float* __restrict__ wkeff, float* __restrict__ cbGT) {
  __shared__ float qg[4][256];
  __shared__ float red_w[256];
  int b0 = bg * 4;
  int j = h * 256 + t;
  float cbv[4], Gv[4], Tv[4];
#pragma unroll
  for (int bi = 0; bi < 4; ++bi) {
    int b = b0 + bi;
    float s1 = 0.f, s2 = 0.f;
#pragma unroll
    for (int i = 0; i < 8; ++i) { s1 += qpart[(b * 8 + i) * 2]; s2 += qpart[(b * 8 + i) * 2 + 1]; }
    float m = s1 * (1.0f / NHD);
    float var = s2 * (1.0f / NHD) - m * m;
    float is = 1.0f / sqrtf(var + EPS);
    float q = (qraw[(size_t)b * NHD + j] - m) * is * gq[j] + betq[j];
    float qgv = q * gk[j];
    qg[bi][t] = qgv;
    cbv[bi] = block_reduce_sum(bk[j] * qgv, red_w, t);
    Gv[bi] = block_reduce_sum(qgv, red_w, t);
    Tv[bi] = block_reduce_sum(q * betk[j], red_w, t);
  }
  float acc[4] = {0.f, 0.f, 0.f, 0.f};
  const float4* wr = (const float4*)(Wk + (size_t)t * NHD + h * 256);
#pragma unroll 2
  for (int d4 = 0; d4 < 64; ++d4) {
    float4 w = wr[d4];
#pragma unroll
    for (int bi = 0; bi < 4; ++bi) {
      acc[bi] += w.x * qg[bi][d4 * 4] + w.y * qg[bi][d4 * 4 + 1]
               + w.z * qg[bi][d4 * 4 + 2] + w.w * qg[bi][d4 * 4 + 3];
    }
  }
#pragma unroll
  for (int bi = 0; bi < 4; ++bi) {
    int b = b0 + bi;
    wkeff[(size_t)(b * NH + h) * ND + t] = acc[bi];
    if (t == 0) { float* p = cbGT + (b * NH + h) * 4; p[0] = cbv[bi]; p[1] = Gv[bi]; p[2] = Tv[bi]; }
  }
}

// ================= merged launchers =================

// kA: blocks [0,512) meta | [512,768) q1 (8h x 32bg) | [768,1056) aat2
__global__ __launch_bounds__(256) void kA(const float* __restrict__ Wk,
                                          const float* __restrict__ bk,
                                          const float* __restrict__ Wv,
                                          const float* __restrict__ bv,
                                          const int* __restrict__ mask_i,
                                          const float* __restrict__ local,
                                          const float* __restrict__ Wq,
                                          const float* __restrict__ bq,
                                          float* __restrict__ kmeta,
                                          float* __restrict__ vmeta,
                                          int* __restrict__ flag,
                                          float* __restrict__ qraw,
                                          float* __restrict__ qpart,
                                          float* __restrict__ MkP,
                                          float* __restrict__ MvP) {
  int bid = blockIdx.x, t = threadIdx.x;
  if (bid < 512) {
    meta_body(bid & 255, bid >> 8, t, Wk, bk, Wv, bv, mask_i, kmeta, vmeta, flag);
  } else if (bid < 768) {
    int id = bid - 512;
    q1_body(id & 7, id >> 3, t, local, Wq, bq, qraw, qpart);
  } else {
    int id = bid - 768;
    aat2_body(id % 36, id / 36, t, Wk, Wv, MkP, MvP);
  }
}

// kB: blocks [0,512) aat_reduce | [512,768) wkeff (8h x 32bg)
__global__ __launch_bounds__(256) void kB(const float* __restrict__ MkP,
                                          const float* __restrict__ MvP,
                                          short* __restrict__ Mkb,
                                          short* __restrict__ Mvb,
                                          const float* __restrict__ qraw,
                                          const float* __restrict__ qpart,
                                          const float* __restrict__ gq,
                                          const float* __restrict__ betq,
                                          const float* __restrict__ Wk,
                                          const float* __restrict__ bk,
                                          const float* __restrict__ gk,
                                          const float* __restrict__ betk,
                                          float* __restrict__ wkeff,
                                          float* __restrict__ cbGT) {
  int bid = blockIdx.x, t = threadIdx.x;
  if (bid < 512) {
    aatred_body(bid & 255, bid >> 8, t, MkP, MvP, Mkb, Mvb);
  } else {
    int id = bid - 512;
    wkeff_body(id & 7, id >> 3, t, qraw, qpart, gq, betq, Wk, bk, gk, betk, wkeff, cbGT);
  }
}

// ---------- K5a (MFMA): LN moments via y = x^T M x, SYMMETRY-REDUCED (r12 best) ----------
__global__ __launch_bounds__(256) void k_moments(const float* __restrict__ dist,
                                                 const float* __restrict__ sites,
                                                 const short* __restrict__ Mkb,
                                                 const short* __restrict__ Mvb,
                                                 const float* __restrict__ kmeta,
                                                 const float* __restrict__ vmeta,
                                                 float* __restrict__ mk_arr,
                                                 float* __restrict__ sk_arr,
                                                 float* __restrict__ mv_arr,
                                                 float* __restrict__ sv_arr) {
  int sel = blockIdx.y;
  const float* X = sel ? sites : dist;
  const short* Mb = sel ? Mvb : Mkb;
  const float* meta = sel ? vmeta : kmeta;
  float* m_out = sel ? mv_arr : mk_arr;
  float* s_out = sel ? sv_arr : sk_arr;

  int t = threadIdx.x;
  int w = t >> 6;
  int l = t & 63;
  int r16 = l & 15;
  int ksub = l >> 4;
  int srow = t >> 4;
  int scc0 = (t & 15) * 8;

  __shared__ __align__(16) short Tb[4][2][16][40];
  __shared__ __align__(16) short Ms[2][16][264];

  for (int cc = scc0; cc < 32; cc += 128)
    *(bf8v*)&Ms[0][srow][cc] = *(const bf8v*)(Mb + ((size_t)srow << 8) + cc);

  size_t rowA = (size_t)blockIdx.x * 128 + w * 32;
  const float* xr0 = X + (rowA + r16) * 256;
  const float* xr1 = xr0 + 16 * 256;

  bf8v af0[8], af1[8];
  float pm0 = 0.f, pl0 = 0.f, pm1 = 0.f, pl1 = 0.f;
#pragma unroll
  for (int kc = 0; kc < 8; ++kc) {
    int c0 = kc * 32 + ksub * 8;
    float4 wa = *(const float4*)(meta + c0);
    float4 wb = *(const float4*)(meta + c0 + 4);
    float4 la = *(const float4*)(meta + 256 + c0);
    float4 lb = *(const float4*)(meta + 256 + c0 + 4);
    float4 x0a = *(const float4*)(xr0 + c0);
    float4 x0b = *(const float4*)(xr0 + c0 + 4);
    float4 x1a = *(const float4*)(xr1 + c0);
    float4 x1b = *(const float4*)(xr1 + c0 + 4);
    pm0 += x0a.x * wa.x + x0a.y * wa.y + x0a.z * wa.z + x0a.w * wa.w
         + x0b.x * wb.x + x0b.y * wb.y + x0b.z * wb.z + x0b.w * wb.w;
    pl0 += x0a.x * la.x + x0a.y * la.y + x0a.z * la.z + x0a.w * la.w
         + x0b.x * lb.x + x0b.y * lb.y + x0b.z * lb.z + x0b.w * lb.w;
    pm1 += x1a.x * wa.x + x1a.y * wa.y + x1a.z * wa.z + x1a.w * wa.w
         + x1b.x * wb.x + x1b.y * wb.y + x1b.z * wb.z + x1b.w * wb.w;
    pl1 += x1a.x * la.x + x1a.y * la.y + x1a.z * la.z + x1a.w * la.w
         + x1b.x * lb.x + x1b.y * lb.y + x1b.z * lb.z + x1b.w * lb.w;
    bf8v a0, a1;
    a0[0] = f2bf(x0a.x); a0[1] = f2bf(x0a.y); a0[2] = f2bf(x0a.z); a0[3] = f2bf(x0a.w);
    a0[4] = f2bf(x0b.x); a0[5] = f2bf(x0b.y); a0[6] = f2bf(x0b.z); a0[7] = f2bf(x0b.w);
    a1[0] = f2bf(x1a.x); a1[1] = f2bf(x1a.y); a1[2] = f2bf(x1a.z); a1[3] = f2bf(x1a.w);
    a1[4] = f2bf(x1b.x); a1[5] = f2bf(x1b.y); a1[6] = f2bf(x1b.z); a1[7] = f2bf(x1b.w);
    af0[kc] = a0;
    af1[kc] = a1;
  }
  pm0 += __shfl_xor(pm0, 16); pm0 += __shfl_xor(pm0, 32);
  pl0 += __shfl_xor(pl0, 16); pl0 += __shfl_xor(pl0, 32);
  pm1 += __shfl_xor(pm1, 16); pm1 += __shfl_xor(pm1, 32);
  pl1 += __shfl_xor(pl1, 16); pl1 += __shfl_xor(pl1, 32);

  __syncthreads();

  f32x4 y0 = {0.f, 0.f, 0.f, 0.f}, y1 = {0.f, 0.f, 0.f, 0.f};

#pragma unroll
  for (int n = 0; n < 16; ++n) {
    if (n < 15) {
      const int nn = n + 1;
      const int ncols = 32 * ((nn >> 1) + 1);
      for (int cc = scc0; cc < ncols; cc += 128)
        *(bf8v*)&Ms[nn & 1][srow][cc] = *(const bf8v*)(Mb + ((size_t)(nn * 16 + srow) << 8) + cc);
    }
    const int kcd = n >> 1;
    f32x4 ta = {0.f, 0.f, 0.f, 0.f}, tb = {0.f, 0.f, 0.f, 0.f};
#pragma unroll
    for (int kc = 0; kc < kcd; ++kc) {
      bf8v bfv = *(const bf8v*)&Ms[n & 1][r16][kc * 32 + ksub * 8];
      ta = __builtin_amdgcn_mfma_f32_16x16x32_bf16(af0[kc], bfv, ta, 0, 0, 0);
      tb = __builtin_amdgcn_mfma_f32_16x16x32_bf16(af1[kc], bfv, tb, 0, 0, 0);
    }
    ta = ta + ta;
    tb = tb + tb;
    {
      bf8v bfd = *(const bf8v*)&Ms[n & 1][r16][kcd * 32 + ksub * 8];
      ta = __builtin_amdgcn_mfma_f32_16x16x32_bf16(af0[kcd], bfd, ta, 0, 0, 0);
      tb = __builtin_amdgcn_mfma_f32_16x16x32_bf16(af1[kcd], bfd, tb, 0, 0, 0);
    }
#pragma unroll
    for (int q = 0; q < 4; ++q) {
      Tb[w][0][ksub * 4 + q][(n & 1) * 16 + r16] = f2bf(ta[q]);
      Tb[w][1][ksub * 4 + q][(n & 1) * 16 + r16] = f2bf(tb[q]);
    }
    if (n & 1) {
      bf8v a20 = *(const bf8v*)&Tb[w][0][r16][ksub * 8];
      bf8v a21 = *(const bf8v*)&Tb[w][1][r16][ksub * 8];
      y0 = __builtin_amdgcn_mfma_f32_16x16x32_bf16(a20, af0[n >> 1], y0, 0, 0, 0);
      y1 = __builtin_amdgcn_mfma_f32_16x16x32_bf16(a21, af1[n >> 1], y1, 0, 0, 0);
    }
    __syncthreads();
  }

  int qs = r16 & 3;
  float yd0 = (qs == 0) ? y0[0] : (qs == 1) ? y0[1] : (qs == 2) ? y0[2] : y0[3];
  float yd1 = (qs == 0) ? y1[0] : (qs == 1) ? y1[1] : (qs == 2) ? y1[2] : y1[3];
  float bbar = meta[512], cc = meta[513];
  if (ksub == (r16 >> 2)) {
    float m0 = pm0 + bbar;
    float var0 = fmaxf(yd0 + (pl0 + cc) - m0 * m0, 0.0f) + EPS;
    m_out[rowA + r16] = m0;
    s_out[rowA + r16] = 1.0f / sqrtf(var0);
    float m1 = pm1 + bbar;
    float var1 = fmaxf(yd1 + (pl1 + cc) - m1 * m1, 0.0f) + EPS;
    m_out[rowA + 16 + r16] = m1;
    s_out[rowA + 16 + r16] = 1.0f / sqrtf(var1);
  }
}

// ---------- K5 (MFMA): fused scores + softmax + PV, one block per b ----------
__global__ __launch_bounds__(512) void k_attn2(const float* __restrict__ dist,
                                               const float* __restrict__ sites,
                                               const int* __restrict__ mask_i,
                                               const int* __restrict__ mflag,
                                               const float* __restrict__ wkeff,
                                               const float* __restrict__ cbGT,
                                               const float* __restrict__ mk_arr,
                                               const float* __restrict__ sk_arr,
                                               const float* __restrict__ mv_arr,
                                               const float* __restrict__ sv_arr,
                                               float* __restrict__ zbuf,
                                               float* __restrict__ bg) {
  int b = blockIdx.x, t = threadIdx.x;
  int w = t >> 6, l = t & 63, r16 = l & 15, ksub = l >> 4;

  __shared__ float us[16][260];
  __shared__ __align__(16) short St[256][72];

  for (int i = t; i < 8 * 260; i += 512) (&us[8][0])[i] = 0.f;

  const int mbytes = mflag[0];

  const float* xr0 = dist + ((size_t)b * NS + w * 32 + r16) * ND;
  const float* xr1 = xr0 + 16 * ND;
  const float* wkp = wkeff + ((size_t)b * NH + (r16 & 7)) * ND;
  f32x4 u0 = {0.f, 0.f, 0.f, 0.f}, u1 = {0.f, 0.f, 0.f, 0.f};
#pragma unroll 2
  for (int kc = 0; kc < 8; ++kc) {
    int c0 = kc * 32 + ksub * 8;
    float4 xa = *(const float4*)(xr0 + c0);
    float4 xb = *(const float4*)(xr0 + c0 + 4);
    float4 ya = *(const float4*)(xr1 + c0);
    float4 yb = *(const float4*)(xr1 + c0 + 4);
    float4 wa = {0.f, 0.f, 0.f, 0.f}, wb = {0.f, 0.f, 0.f, 0.f};
    if (r16 < 8) { wa = *(const float4*)(wkp + c0); wb = *(const float4*)(wkp + c0 + 4); }
    bf8v xh, xl, yh, yl, wh, wl;
    split8(xa, xb, xh, xl);
    split8(ya, yb, yh, yl);
    split8(wa, wb, wh, wl);
    u0 = __builtin_amdgcn_mfma_f32_16x16x32_bf16(xh, wh, u0, 0, 0, 0);
    u0 = __builtin_amdgcn_mfma_f32_16x16x32_bf16(xl, wh, u0, 0, 0, 0);
    u0 = __builtin_amdgcn_mfma_f32_16x16x32_bf16(xh, wl, u0, 0, 0, 0);
    u1 = __builtin_amdgcn_mfma_f32_16x16x32_bf16(yh, wh, u1, 0, 0, 0);
    u1 = __builtin_amdgcn_mfma_f32_16x16x32_bf16(yl, wh, u1, 0, 0, 0);
    u1 = __builtin_amdgcn_mfma_f32_16x16x32_bf16(yh, wl, u1, 0, 0, 0);
  }

  float cb = 0.f, G = 0.f, T = 0.f;
  if (r16 < 8) { const float* p = cbGT + (b * NH + r16) * 4; cb = p[0]; G = p[1]; T = p[2]; }
  const unsigned char* mask_b = (const unsigned char*)mask_i;
#pragma unroll
  for (int g = 0; g < 2; ++g) {
    f32x4 uu = g ? u1 : u0;
    int base = w * 32 + g * 16 + ksub * 4;
    float4 mk4 = *(const float4*)(mk_arr + b * NS + base);
    float4 sk4 = *(const float4*)(sk_arr + b * NS + base);
    int mm[4];
    if (mbytes) {
      mm[0] = mask_b[b * NS + base];     mm[1] = mask_b[b * NS + base + 1];
      mm[2] = mask_b[b * NS + base + 2]; mm[3] = mask_b[b * NS + base + 3];
    } else {
      mm[0] = mask_i[b * NS + base];     mm[1] = mask_i[b * NS + base + 1];
      mm[2] = mask_i[b * NS + base + 2]; mm[3] = mask_i[b * NS + base + 3];
    }
    const float* mkp = (const float*)&mk4;
    const float* skp = (const float*)&sk4;
#pragma unroll
    for (int q = 0; q < 4; ++q) {
      float u = ((uu[q] + cb - mkp[q] * G) * skp[q] + T) * 0.0625f;
      if (mm[q]) u = -1e30f;
      if (r16 < 8) us[r16][base + q] = u;
    }
  }
  __syncthreads();

  {
    int h = w;
    float v[4];
#pragma unroll
    for (int i = 0; i < 4; ++i) v[i] = us[h][l + 64 * i];
    float mx = fmaxf(fmaxf(v[0], v[1]), fmaxf(v[2], v[3]));
    for (int off = 32; off > 0; off >>= 1) mx = fmaxf(mx, __shfl_xor(mx, off));
    float sum = 0.f;
#pragma unroll
    for (int i = 0; i < 4; ++i) { v[i] = expf(v[i] - mx); sum += v[i]; }
    for (int off = 32; off > 0; off >>= 1) sum += __shfl_xor(sum, off);
    float inv = 1.0f / sum;
    float bp = 0.f, gp = 0.f;
#pragma unroll
    for (int i = 0; i < 4; ++i) {
      int s = l + 64 * i;
      float a = v[i] * inv;
      float sv = sv_arr[b * NS + s];
      float mv = mv_arr[b * NS + s];
      float wv = a * sv;
      us[h][s] = wv;
      bp += wv;
      gp += wv * mv;
    }
    for (int off = 32; off > 0; off >>= 1) { bp += __shfl_xor(bp, off); gp += __shfl_xor(gp, off); }
    if (l == 0) { float* p = bg + (b * NH + h) * 2; p[0] = bp; p[1] = gp; }
  }
  __syncthreads();

  f32x4 z0 = {0.f, 0.f, 0.f, 0.f}, z1 = {0.f, 0.f, 0.f, 0.f};
  int half = t >> 8, tc = t & 255;
  for (int chunk = 0; chunk < 4; ++chunk) {
    const float* Sp = sites + ((size_t)b * NS + chunk * 64) * ND + tc;
#pragma unroll
    for (int it = 0; it < 4; ++it) {
      int s8 = (half * 4 + it) * 8;
      bf8v vtmp;
#pragma unroll
      for (int j = 0; j < 8; ++j) vtmp[j] = f2bf(Sp[(size_t)(s8 + j) * ND]);
      *(bf8v*)&St[tc][s8] = vtmp;
    }
    __syncthreads();
#pragma unroll
    for (int kst = 0; kst < 2; ++kst) {
      int sg = chunk * 64 + kst * 32 + ksub * 8;
      int sl0 = kst * 32 + ksub * 8;
      float4 p0 = *(const float4*)&us[r16][sg];
      float4 p1 = *(const float4*)&us[r16][sg + 4];
      bf8v ah, al;
      split8(p0, p1, ah, al);
      bf8v b0 = *(const bf8v*)&St[(2 * w) * 16 + r16][sl0];
      bf8v b1 = *(const bf8v*)&St[(2 * w + 1) * 16 + r16][sl0];
      z0 = __builtin_amdgcn_mfma_f32_16x16x32_bf16(ah, b0, z0, 0, 0, 0);
      z0 = __builtin_amdgcn_mfma_f32_16x16x32_bf16(al, b0, z0, 0, 0, 0);
      z1 = __builtin_amdgcn_mfma_f32_16x16x32_bf16(ah, b1, z1, 0, 0, 0);
      z1 = __builtin_amdgcn_mfma_f32_16x16x32_bf16(al, b1, z1, 0, 0, 0);
    }
    __syncthreads();
  }
  if (ksub < 2) {
#pragma unroll
    for (int q = 0; q < 4; ++q) {
      int h = ksub * 4 + q;
      zbuf[((size_t)b * NH + h) * ND + 2 * w * 16 + r16] = z0[q];
      zbuf[((size_t)b * NH + h) * ND + (2 * w + 1) * 16 + r16] = z1[q];
    }
  }
}

// ---------- K6a: o = z@Wv + corrections + residual, 4 batches/block (Wv traffic /4) ----------
__global__ __launch_bounds__(256) void k_o1(const float* __restrict__ zbuf,
                                            const float* __restrict__ bg,
                                            const float* __restrict__ qraw,
                                            const float* __restrict__ qpart,
                                            const float* __restrict__ gq,
                                            const float* __restrict__ betq,
                                            const float* __restrict__ Wv,
                                            const float* __restrict__ bv,
                                            const float* __restrict__ gv,
                                            const float* __restrict__ betv,
                                            float* __restrict__ o_buf,
                                            float* __restrict__ part1) {
  int h = blockIdx.x, bg4 = blockIdx.y, t = threadIdx.x;
  __shared__ float zs[4][256];
  __shared__ float red[256];
  int b0 = bg4 * 4;
#pragma unroll
  for (int bi = 0; bi < 4; ++bi)
    zs[bi][t] = zbuf[((size_t)(b0 + bi) * NH + h) * ND + t];
  __syncthreads();
  int j = h * 256 + t;
  float acc[4] = {0.f, 0.f, 0.f, 0.f};
  const float* W = Wv + j;
  for (int c = 0; c < 256; ++c) {
    float wv = W[(size_t)c * NHD];
#pragma unroll
    for (int bi = 0; bi < 4; ++bi) acc[bi] = fmaf(zs[bi][c], wv, acc[bi]);
  }
#pragma unroll
  for (int bi = 0; bi < 4; ++bi) {
    int b = b0 + bi;
    float qs1 = 0.f, qs2 = 0.f;
#pragma unroll
    for (int i = 0; i < 8; ++i) { qs1 += qpart[(b * 8 + i) * 2]; qs2 += qpart[(b * 8 + i) * 2 + 1]; }
    float qm = qs1 * (1.0f / NHD);
    float qvar = qs2 * (1.0f / NHD) - qm * qm;
    float qis = 1.0f / sqrtf(qvar + EPS);
    float bets = bg[(b * NH + h) * 2], gams = bg[(b * NH + h) * 2 + 1];
    float qln = (qraw[(size_t)b * NHD + j] - qm) * qis * gq[j] + betq[j];
    float o = gv[j] * (acc[bi] + bv[j] * bets - gams) + betv[j] + qln;
    o_buf[(size_t)b * NHD + j] = o;
    float s1 = block_reduce_sum(o, red, t);
    float s2 = block_reduce_sum(o * o, red, t);
    if (t == 0) { part1[(b * 8 + h) * 2] = s1; part1[(b * 8 + h) * 2 + 1] = s2; }
  }
}

// ---------- K6b: y1 = LN1(o); split-K partials of y1@Wo, 4 batches/block ----------
__global__ __launch_bounds__(256) void k_o2(const float* __restrict__ o_buf,
                                            const float* __restrict__ part1,
                                            const float* __restrict__ g1,
                                            const float* __restrict__ b1,
                                            const float* __restrict__ Wo,
                                            float* __restrict__ part2) {
  int ks = blockIdx.x, bg4 = blockIdx.y, t = threadIdx.x;
  __shared__ float y1s[4][256];
  int b0 = bg4 * 4;
  int jj = ks * 256 + t;
#pragma unroll
  for (int bi = 0; bi < 4; ++bi) {
    int b = b0 + bi;
    float s1 = 0.f, s2 = 0.f;
#pragma unroll
    for (int i = 0; i < 8; ++i) { s1 += part1[(b * 8 + i) * 2]; s2 += part1[(b * 8 + i) * 2 + 1]; }
    float m = s1 * (1.0f / NHD);
    float var = s2 * (1.0f / NHD) - m * m;
    float is = 1.0f / sqrtf(var + EPS);
    y1s[bi][t] = (o_buf[(size_t)b * NHD + jj] - m) * is * g1[jj] + b1[jj];
  }
  __syncthreads();
  float acc[4] = {0.f, 0.f, 0.f, 0.f};
  const float* W = Wo + (size_t)ks * 256 * 256 + t;
  for (int i = 0; i < 256; ++i) {
    float wv = W[(size_t)i * 256];
#pragma unroll
    for (int bi = 0; bi < 4; ++bi) acc[bi] = fmaf(y1s[bi][i], wv, acc[bi]);
  }
#pragma unroll
  for (int bi = 0; bi < 4; ++bi)
    part2[((size_t)ks * NB + b0 + bi) * 256 + t] = acc[bi];
}

// ---------- K6c: reduce split-K, bias, LN2, write outputs ----------
__global__ __launch_bounds__(256) void k_o3(const float* __restrict__ part2,
                                            const float* __restrict__ bo,
                                            const float* __restrict__ g2,
                                            const float* __restrict__ b2,
                                            const float* __restrict__ beta_a,
                                            float* __restrict__ out) {
  int b = blockIdx.x, t = threadIdx.x;
  __shared__ float red[256];
  float acc = bo[t];
#pragma unroll
  for (int ks = 0; ks < 8; ++ks) acc += part2[((size_t)ks * NB + b) * 256 + t];
  float q1 = block_reduce_sum(acc, red, t);
  float q2 = block_reduce_sum(acc * acc, red, t);
  float m2 = q1 * (1.0f / 256.0f);
  float v2 = q2 * (1.0f / 256.0f) - m2 * m2;
  float is2 = 1.0f / sqrtf(v2 + EPS);
  out[NB * NS + b * 256 + t] = (acc - m2) * is2 * g2[t] + b2[t];
  out[b * 256 + t] = beta_a[0];
}

extern "C" void kernel_launch(void* const* d_in, const int* in_sizes, int n_in,
                              void* d_out, int out_size, void* d_ws, size_t ws_size,
                              hipStream_t stream) {
  (void)in_sizes; (void)n_in; (void)out_size; (void)ws_size;
  const float* local = (const float*)d_in[0];
  const float* dist  = (const float*)d_in[1];
  const float* sites = (const float*)d_in[2];
  const int*   mask  = (const int*)d_in[3];
  const float* Wq   = (const float*)d_in[4];
  const float* bq   = (const float*)d_in[5];
  const float* gq   = (const float*)d_in[6];
  const float* betq = (const float*)d_in[7];
  const float* Wk   = (const float*)d_in[8];
  const float* bk   = (const float*)d_in[9];
  const float* gk   = (const float*)d_in[10];
  const float* betk = (const float*)d_in[11];
  const float* Wv   = (const float*)d_in[12];
  const float* bv   = (const float*)d_in[13];
  const float* gv   = (const float*)d_in[14];
  const float* betv = (const float*)d_in[15];
  const float* g1   = (const float*)d_in[16];
  const float* b1   = (const float*)d_in[17];
  const float* Wo   = (const float*)d_in[18];
  const float* bo   = (const float*)d_in[19];
  const float* g2   = (const float*)d_in[20];
  const float* b2   = (const float*)d_in[21];
  const float* beta_a = (const float*)d_in[25];
  float* out = (float*)d_out;

  float* ws = (float*)d_ws;
  float* MkP   = ws;                // 262144
  float* MvP   = MkP + 262144;      // 262144 (later aliased: part2)
  short* Mkb   = (short*)(MvP + 262144);   // 65536 shorts
  short* Mvb   = Mkb + 65536;              // 65536 shorts
  float* kmeta = (float*)(Mvb + 65536);    // 1024
  float* vmeta = kmeta + 1024;      // 1024
  float* qraw  = vmeta + 1024;      // 262144 (also written as o_buf by k_o1)
  float* wkeff = qraw + 262144;     // 262144
  float* cbGT  = wkeff + 262144;    // 4096
  float* mk_arr = cbGT + 4096;      // 32768
  float* sk_arr = mk_arr + 32768;   // 32768
  float* mv_arr = sk_arr + 32768;   // 32768
  float* sv_arr = mv_arr + 32768;   // 32768
  float* zbuf  = sv_arr + 32768;    // 262144
  float* bg    = zbuf + 262144;     // 2048
  int*   mflag = (int*)(bg + 2048); // 16 ints
  float* part1 = (float*)(mflag + 16); // 2048
  float* qpart = part1 + 2048;      // 2048

  float* o_buf = qraw;   // k_o1 thread-local read-then-write, safe alias
  float* part2 = MvP;    // live k_o2..k_o3 (MvP dead after kB)

  kA<<<dim3(1056), dim3(256), 0, stream>>>(Wk, bk, Wv, bv, mask, local, Wq, bq,
                                           kmeta, vmeta, mflag, qraw, qpart, MkP, MvP);
  kB<<<dim3(768), dim3(256), 0, stream>>>(MkP, MvP, Mkb, Mvb, qraw, qpart, gq, betq,
                                          Wk, bk, gk, betk, wkeff, cbGT);
  k_moments<<<dim3(256, 2), dim3(256), 0, stream>>>(dist, sites, Mkb, Mvb, kmeta, vmeta,
                                                    mk_arr, sk_arr, mv_arr, sv_arr);
  k_attn2<<<dim3(128), dim3(512), 0, stream>>>(dist, sites, mask, mflag, wkeff, cbGT,
                                               mk_arr, sk_arr, mv_arr, sv_arr, zbuf, bg);
  k_o1<<<dim3(8, 32), dim3(256), 0, stream>>>(zbuf, bg, qraw, qpart, gq, betq,
                                              Wv, bv, gv, betv, o_buf, part1);
  k_o2<<<dim3(8, 32), dim3(256), 0, stream>>>(o_buf, part1, g1, b1, Wo, part2);
  k_o3<<<dim3(128), dim3(256), 0, stream>>>(part2, bo, g2, b2, beta_a, out);
}